// Round 10
// baseline (43.843 us; speedup 1.0000x reference)
//
#include <hip/hip_runtime.h>

typedef unsigned short u16;
typedef unsigned int u32;
typedef __bf16 bf16x8 __attribute__((ext_vector_type(8)));
typedef unsigned short ushort8 __attribute__((ext_vector_type(8)));
typedef float f32x4 __attribute__((ext_vector_type(4)));

#define DEV_INLINE __device__ __forceinline__

constexpr int NB = 4;        // batches
constexpr int NAG = 4096;    // agents per batch
constexpr int ROWS = NB * NAG;
constexpr int GRID = 20;     // bin grid (cell size 1.0 >= radius)
constexpr int CELLS = GRID * GRID;
constexpr int CSTRIDE = 404;
constexpr int MAXNB = 128;   // per-agent neighbor cap (lambda ~32)

DEV_INLINE u16 f2bu(float x) { __bf16 h = (__bf16)x; return __builtin_bit_cast(u16, h); }
DEV_INLINE float bu2f(u16 u) { return __builtin_bit_cast(float, ((u32)u) << 16); }
DEV_INLINE u32 pack2(float a, float b) { return (u32)f2bu(a) | ((u32)f2bu(b) << 16); }

DEV_INLINE f32x4 MF(bf16x8 a, const u16* p, f32x4 c) {
  ushort8 bu = *(const ushort8*)p;
  return __builtin_amdgcn_mfma_f32_16x16x32_bf16(a, __builtin_bit_cast(bf16x8, bu), c, 0, 0, 0);
}

template<bool BF>
DEV_INLINE bf16x8 loadA(const void* __restrict__ src, int row, int c) {
  if constexpr (BF) {
    ushort8 u = *reinterpret_cast<const ushort8*>((const u16*)src + (size_t)row * 64 + c);
    return __builtin_bit_cast(bf16x8, u);
  } else {
    const float* f = (const float*)src + (size_t)row * 64 + c;
    f32x4 a = *(const f32x4*)f;
    f32x4 b = *(const f32x4*)(f + 4);
    bf16x8 r;
    r[0] = (__bf16)a[0]; r[1] = (__bf16)a[1]; r[2] = (__bf16)a[2]; r[3] = (__bf16)a[3];
    r[4] = (__bf16)b[0]; r[5] = (__bf16)b[1]; r[6] = (__bf16)b[2]; r[7] = (__bf16)b[3];
    return r;
  }
}

// ================= K1: binning (blocks 0..3) | mlp1 (4..259) | W3-6 transpose (260..263)
// wts layout (u16): W3T[128n][128k]@0, W4T[64n][128k]@16384, W5T[128n][128k]@24576, W6T[64n][128k]@40960.
// (verbatim from round 9 — passed, conflict-free two-stage transpose)
__global__ __launch_bounds__(1024) void fused_setup_mlp1(
    const float* __restrict__ pos, const float* __restrict__ states,
    const float* __restrict__ W1, const float* __restrict__ b1,
    const float* __restrict__ W2, const float* __restrict__ b2,
    const float* __restrict__ W3, const float* __restrict__ W4,
    const float* __restrict__ W5, const float* __restrict__ W6,
    u16* __restrict__ wts, u16* __restrict__ msgs,
    float2* __restrict__ pos_sorted, int* __restrict__ cell_start,
    int* __restrict__ sid)
{
  extern __shared__ u16 smem[];
  const int tid = threadIdx.x;
  const int lane = tid & 63;
  const int wave = tid >> 6;
  const int bid = blockIdx.x;

  if (bid < NB) {
    int* cnt_s = (int*)smem;
    int* start_s = cnt_s + CELLS;
    u16* cell_of = (u16*)(start_s + CELLS + 1);
    u16* rank_of = cell_of + NAG;
    const float2* pb = (const float2*)(pos + (size_t)bid * NAG * 2);
    for (int c = tid; c < CELLS; c += 1024) cnt_s[c] = 0;
    __syncthreads();
    for (int i = tid; i < NAG; i += 1024) {
      float2 p = pb[i];
      int cx = min(max((int)floorf(p.x), 0), GRID - 1);
      int cy = min(max((int)floorf(p.y), 0), GRID - 1);
      int c = cy * GRID + cx;
      rank_of[i] = (u16)atomicAdd(&cnt_s[c], 1);
      cell_of[i] = (u16)c;
    }
    __syncthreads();
    if (wave == 0) {
      int carry = 0;
      for (int g = 0; g < CELLS; g += 64) {
        int c = g + lane;
        int x = (c < CELLS) ? cnt_s[c] : 0;
#pragma unroll
        for (int off = 1; off < 64; off <<= 1) {
          int y = __shfl_up(x, off, 64);
          if (lane >= off) x += y;
        }
        if (c < CELLS) start_s[c + 1] = carry + x;
        carry += __shfl(x, 63, 64);
      }
      if (lane == 0) start_s[0] = 0;
    }
    __syncthreads();
    for (int c = tid; c <= CELLS; c += 1024) cell_start[bid * CSTRIDE + c] = start_s[c];
    for (int i = tid; i < NAG; i += 1024) {
      int kk = start_s[cell_of[i]] + (int)rank_of[i];
      sid[bid * NAG + kk] = bid * NAG + i;
      pos_sorted[bid * NAG + kk] = pb[i];
    }
    return;
  }

  if (bid >= NB + 256) {
    const int base = (bid - (NB + 256)) * 12288;
#pragma unroll
    for (int t = 0; t < 12; ++t) {
      int idx = base + t * 1024 + tid;
      const float* src; int n, k, Nc;
      if (idx < 16384)      { src = W3; n = idx >> 7; k = idx & 127; Nc = 128; }
      else if (idx < 24576) { int li = idx - 16384; src = W4; n = li >> 7; k = li & 127; Nc = 64; }
      else if (idx < 40960) { int li = idx - 24576; src = W5; n = li >> 7; k = li & 127; Nc = 128; }
      else                  { int li = idx - 40960; src = W6; n = li >> 7; k = li & 127; Nc = 64; }
      wts[idx] = f2bu(src[k * Nc + n]);
    }
    return;
  }

  // ---------- mlp1 ----------
  u16* WaTs = smem;              // [128][72]
  u16* WbTs = smem + 9216;       // [64][136]
  u16* ovl  = smem + 17920;      // overlay

  const int l15 = lane & 15;
  const int khalf = (lane >> 4) * 8;
  const int rg = wave >> 2;
  const int cq = wave & 3;
  const int rb = (bid - NB) * 64 + rg * 16;
  const int row = rb + l15;

  bf16x8 aS[2];
  aS[0] = loadA<false>(states, row, khalf);
  aS[1] = loadA<false>(states, row, 32 + khalf);

  for (int t = tid; t < 4096; t += 1024) {
    const int e = t * 2;
    const int k = e >> 7, n = e & 127;
    const float2 v = *(const float2*)&W1[e];
    *(u32*)&ovl[k * 132 + n] = pack2(v.x, v.y);
  }
  __syncthreads();
  {
    const int n = tid & 127, g = tid >> 7;
    ushort8 v;
#pragma unroll
    for (int j = 0; j < 8; ++j) v[j] = ovl[(g * 8 + j) * 132 + n];
    *(ushort8*)&WaTs[n * 72 + g * 8] = v;
  }
  __syncthreads();
  for (int t = tid; t < 4096; t += 1024) {
    const int e = t * 2;
    const int k = e >> 6, n = e & 63;
    const float2 v = *(const float2*)&W2[e];
    *(u32*)&ovl[k * 68 + n] = pack2(v.x, v.y);
  }
  __syncthreads();
  {
    const int n = tid & 63, g = tid >> 6;
    ushort8 v;
#pragma unroll
    for (int j = 0; j < 8; ++j) v[j] = ovl[(g * 8 + j) * 68 + n];
    *(ushort8*)&WbTs[n * 136 + g * 8] = v;
  }
  __syncthreads();

  u16* hs = ovl + rg * 2176;

  f32x4 acc1[2] = {};
#pragma unroll
  for (int kt = 0; kt < 2; ++kt) {
#pragma unroll
    for (int j = 0; j < 2; ++j) {
      const int nt = cq * 2 + j;
      acc1[j] = MF(aS[kt], &WaTs[(nt * 16 + l15) * 72 + kt * 32 + khalf], acc1[j]);
    }
  }
#pragma unroll
  for (int j = 0; j < 2; ++j) {
    const int col = (cq * 2 + j) * 16 + l15;
    const float bv = b1[col];
#pragma unroll
    for (int r = 0; r < 4; ++r)
      hs[((lane >> 4) * 4 + r) * 136 + col] = f2bu(fmaxf(acc1[j][r] + bv, 0.0f));
  }
  __syncthreads();

  f32x4 acc2 = {};
#pragma unroll
  for (int kt = 0; kt < 4; ++kt) {
    ushort8 au = *(const ushort8*)&hs[l15 * 136 + kt * 32 + khalf];
    acc2 = MF(__builtin_bit_cast(bf16x8, au),
              &WbTs[(cq * 16 + l15) * 136 + kt * 32 + khalf], acc2);
  }
  {
    const int col = cq * 16 + l15;
    const float bv = b2[col];
#pragma unroll
    for (int r = 0; r < 4; ++r)
      msgs[(size_t)(rb + (lane >> 4) * 4 + r) * 64 + col] = f2bu(acc2[r] + bv);
  }
}

// ================= K2: fused agg + MLP2 + MLP3, low-LDS phased weights.
// 256 blocks x 1024 thr, 64 rows/block, 78.8 KB LDS.
// LDS (u16): Wa[128][136]@0 (W3 then W5), Wb[64][136]@17408 (W4 then W6),
//            hsr[8704]@26112 (idx overlay -> hs[4][16][136]),
//            fsr[4608]@34816 (agg_s[64][72] -> fs[64][72]).
__global__ __launch_bounds__(1024, 4) void agg_mlp23_kernel(
    const float* __restrict__ states, const float* __restrict__ pos,
    const u16* __restrict__ msgs, const u16* __restrict__ wts,
    const float2* __restrict__ pos_sorted, const int* __restrict__ cell_start,
    const int* __restrict__ sid, const int* __restrict__ radius_ptr,
    const float* __restrict__ b3, const float* __restrict__ b4,
    const float* __restrict__ b5, const float* __restrict__ b6,
    float* __restrict__ out)
{
  extern __shared__ u16 smem[];
  u16* Wa  = smem;             // [128][136]
  u16* Wb  = smem + 17408;     // [64][136]
  u16* hsr = smem + 26112;     // [8704]
  u16* fsr = smem + 34816;     // [4608] = [64][72]

  const int tid = threadIdx.x;
  const int lane = tid & 63;
  const int wave = tid >> 6;       // 0..15
  const int rg = wave >> 2;        // row-group 0..3
  const int cq = wave & 3;         // col-quarter 0..3
  const int l15 = lane & 15;
  const int khalf = (lane >> 4) * 8;
  const int rb0 = blockIdx.x * 64;
  const int rb = rb0 + rg * 16;
  const int row = rb + l15;

  // ---- prefetch global A-frags ----
  bf16x8 aM[2], aS[2];
  aM[0] = loadA<true>(msgs, row, khalf);
  aM[1] = loadA<true>(msgs, row, 32 + khalf);
  aS[0] = loadA<false>(states, row, khalf);
  aS[1] = loadA<false>(states, row, 32 + khalf);

  // ---- stage W3 -> Wa, W4 -> Wb (3072 b128 over 1024 thr) ----
  for (int t = tid; t < 3072; t += 1024) {
    const int e = t * 8;
    ushort8 v = *(const ushort8*)&wts[e];
    u16* dst;
    if (e < 16384) dst = &Wa[(e >> 7) * 136 + (e & 127)];
    else { int li = e - 16384; dst = &Wb[(li >> 7) * 136 + (li & 127)]; }
    *(ushort8*)dst = v;
  }

  // ---- agg phase: 4 rows per wave; idx in hsr, result rows into fsr ----
  {
    const float r = (float)(*radius_ptr);
    const float r2 = __fmul_rn(r, r);
    const unsigned long long lt = (1ull << lane) - 1ull;
    u16* idxw = hsr + wave * (4 * MAXNB);    // [4][128]
#pragma unroll 1
    for (int a = 0; a < 4; ++a) {
      const int gi = rb0 + wave * 4 + a;     // orig global row
      const int b = gi >> 12;
      const int il = gi & (NAG - 1);
      const float2 pk = ((const float2*)pos)[(size_t)b * NAG + il];
      const int cx = min(max((int)floorf(pk.x), 0), GRID - 1);
      const int cy = min(max((int)floorf(pk.y), 0), GRID - 1);
      const int* cs = cell_start + b * CSTRIDE;
      const int* sb = sid + b * NAG;
      const float2* pb = pos_sorted + (size_t)b * NAG;
      int cnt = 0;
#pragma unroll
      for (int dy = -1; dy <= 1; ++dy) {
        const int yy = cy + dy;
        if (yy < 0 || yy >= GRID) continue;
        const int x0 = max(cx - 1, 0), x1 = min(cx + 1, GRID - 1);
        const int c0 = cs[yy * GRID + x0];
        const int c1 = cs[yy * GRID + x1 + 1];
        for (int base = c0; base < c1; base += 64) {
          const int j = base + lane;
          bool ok = false; int sbj = 0;
          if (j < c1) {
            const float2 pj = pb[j];
            sbj = sb[j];
            const float dx_ = pk.x - pj.x;
            const float dy_ = pk.y - pj.y;
            const float d2 = __fadd_rn(__fmul_rn(dx_, dx_), __fmul_rn(dy_, dy_));
            ok = (d2 < r2) && (sbj != gi);
          }
          const unsigned long long m = __ballot(ok);
          if (ok) {
            const int p = cnt + __popcll(m & lt);
            if (p < MAXNB) idxw[a * MAXNB + p] = (u16)sbj;
          }
          cnt += (int)__popcll(m);
        }
      }
      float acc = 0.0f;
      const int n = min(cnt, MAXNB);
      for (int g = 0; g < n; g += 8) {
        ushort8 ii = *(const ushort8*)&idxw[a * MAXNB + g];
        float vs[8];
#pragma unroll
        for (int s = 0; s < 8; ++s) {
          const int jj = (g + s < n) ? (int)ii[s] : (int)ii[0];
          vs[s] = bu2f(msgs[(size_t)jj * 64 + lane]);
        }
#pragma unroll
        for (int s = 0; s < 8; ++s) acc += (g + s < n) ? vs[s] : 0.0f;
      }
      const float inv = 1.0f / (float)(cnt > 0 ? cnt : 1);
      fsr[(wave * 4 + a) * 72 + lane] = f2bu(acc * inv);   // agg tile
    }
  }
  __syncthreads();   // b1: staging + agg + idx reads all done

  u16* hs = hsr + rg * 2176;   // [16][136]

  // ---- GEMM1: hs[:, cq*32..+32] = relu([msgs|agg] @ W3 + b3) ----
  f32x4 acc1[2] = {};
#pragma unroll
  for (int kt = 0; kt < 4; ++kt) {
    bf16x8 a;
    if (kt < 2) a = aM[kt];
    else {
      ushort8 au = *(const ushort8*)&fsr[(rg * 16 + l15) * 72 + (kt - 2) * 32 + khalf];
      a = __builtin_bit_cast(bf16x8, au);
    }
#pragma unroll
    for (int j = 0; j < 2; ++j) {
      const int nt = cq * 2 + j;
      acc1[j] = MF(a, &Wa[(nt * 16 + l15) * 136 + kt * 32 + khalf], acc1[j]);
    }
  }
#pragma unroll
  for (int j = 0; j < 2; ++j) {
    const int col = (cq * 2 + j) * 16 + l15;
    const float bv = b3[col];
#pragma unroll
    for (int r = 0; r < 4; ++r)
      hs[((lane >> 4) * 4 + r) * 136 + col] = f2bu(fmaxf(acc1[j][r] + bv, 0.0f));
  }
  __syncthreads();   // b2: hs ready; W3/agg reads done

  // ---- re-stage W5 -> Wa (hidden under GEMM2) ----
  for (int t = tid; t < 2048; t += 1024) {
    const int e = t * 8;
    ushort8 v = *(const ushort8*)&wts[24576 + e];
    *(ushort8*)&Wa[(e >> 7) * 136 + (e & 127)] = v;
  }
  // ---- GEMM2: fs[:, cq*16..+16] = hs @ W4 + b4 (overwrites agg tile) ----
  f32x4 acc2 = {};
#pragma unroll
  for (int kt = 0; kt < 4; ++kt) {
    ushort8 au = *(const ushort8*)&hs[l15 * 136 + kt * 32 + khalf];
    acc2 = MF(__builtin_bit_cast(bf16x8, au),
              &Wb[(cq * 16 + l15) * 136 + kt * 32 + khalf], acc2);
  }
  {
    const int col = cq * 16 + l15;
    const float bv = b4[col];
#pragma unroll
    for (int r = 0; r < 4; ++r)
      fsr[((rg * 16) + (lane >> 4) * 4 + r) * 72 + col] = f2bu(acc2[r] + bv);
  }
  __syncthreads();   // b3: fs + W5 ready; W4/hs reads done

  // ---- re-stage W6 -> Wb ----
  {
    const int e = tid * 8;
    ushort8 v = *(const ushort8*)&wts[40960 + e];
    *(ushort8*)&Wb[(e >> 7) * 136 + (e & 127)] = v;
  }
  // ---- GEMM3: hs[:, cq*32..+32] = relu([states|fs] @ W5 + b5) ----
  f32x4 acc3[2] = {};
#pragma unroll
  for (int kt = 0; kt < 4; ++kt) {
    bf16x8 a;
    if (kt < 2) a = aS[kt];
    else {
      ushort8 au = *(const ushort8*)&fsr[(rg * 16 + l15) * 72 + (kt - 2) * 32 + khalf];
      a = __builtin_bit_cast(bf16x8, au);
    }
#pragma unroll
    for (int j = 0; j < 2; ++j) {
      const int nt = cq * 2 + j;
      acc3[j] = MF(a, &Wa[(nt * 16 + l15) * 136 + kt * 32 + khalf], acc3[j]);
    }
  }
#pragma unroll
  for (int j = 0; j < 2; ++j) {
    const int col = (cq * 2 + j) * 16 + l15;
    const float bv = b5[col];
#pragma unroll
    for (int r = 0; r < 4; ++r)
      hs[((lane >> 4) * 4 + r) * 136 + col] = f2bu(fmaxf(acc3[j][r] + bv, 0.0f));
  }
  __syncthreads();   // b4: hs(v2) + W6 ready

  // ---- GEMM4: out[:, cq*16..+16] = hs @ W6 + b6 + states ----
  f32x4 acc4 = {};
#pragma unroll
  for (int kt = 0; kt < 4; ++kt) {
    ushort8 au = *(const ushort8*)&hs[l15 * 136 + kt * 32 + khalf];
    acc4 = MF(__builtin_bit_cast(bf16x8, au),
              &Wb[(cq * 16 + l15) * 136 + kt * 32 + khalf], acc4);
  }
  {
    const int col = cq * 16 + l15;
    const float bv = b6[col];
#pragma unroll
    for (int r = 0; r < 4; ++r) {
      const int m = (lane >> 4) * 4 + r;
      const size_t o = (size_t)(rb + m) * 64 + col;
      out[o] = acc4[r] + bv + states[o];
    }
  }
}

// ================= launch
extern "C" void kernel_launch(void* const* d_in, const int* in_sizes, int n_in,
                              void* d_out, int out_size, void* d_ws, size_t ws_size,
                              hipStream_t stream) {
  const float* states = (const float*)d_in[0];
  const float* pos    = (const float*)d_in[1];
  const int*   radius = (const int*)d_in[2];
  const float* W1 = (const float*)d_in[3];
  const float* b1 = (const float*)d_in[4];
  const float* W2 = (const float*)d_in[5];
  const float* b2 = (const float*)d_in[6];
  const float* W3 = (const float*)d_in[7];
  const float* b3 = (const float*)d_in[8];
  const float* W4 = (const float*)d_in[9];
  const float* b4 = (const float*)d_in[10];
  const float* W5 = (const float*)d_in[11];
  const float* b5 = (const float*)d_in[12];
  const float* W6 = (const float*)d_in[13];
  const float* b6 = (const float*)d_in[14];
  float* out = (float*)d_out;

  u16* ws16 = (u16*)d_ws;
  u16* msgs = ws16;                         // [ROWS][64] bf16 (orig order)
  u16* wts  = msgs + (size_t)ROWS * 64;     // 49152 bf16 W3T..W6T
  char* pbyte = (char*)(wts + 49152);
  float2* pos_sorted = (float2*)pbyte;                 // ROWS float2
  int* cell_start = (int*)(pbyte + (size_t)ROWS * 8);  // NB*CSTRIDE
  int* sid = cell_start + NB * CSTRIDE;                // ROWS

  constexpr int LDS_K1 = 26624 * 2;        // 53248
  constexpr int LDS_K2 = 39424 * 2;        // 78848

  fused_setup_mlp1<<<NB + 256 + 4, 1024, LDS_K1, stream>>>(
      pos, states, W1, b1, W2, b2, W3, W4, W5, W6,
      wts, msgs, pos_sorted, cell_start, sid);

  agg_mlp23_kernel<<<ROWS / 64, 1024, LDS_K2, stream>>>(
      states, pos, msgs, wts, pos_sorted, cell_start, sid, radius,
      b3, b4, b5, b6, out);
}

// Round 11
// 41.884 us; speedup vs baseline: 1.0468x; 1.0468x over previous
//
#include <hip/hip_runtime.h>

typedef unsigned short u16;
typedef unsigned int u32;
typedef __bf16 bf16x8 __attribute__((ext_vector_type(8)));
typedef unsigned short ushort8 __attribute__((ext_vector_type(8)));
typedef float f32x4 __attribute__((ext_vector_type(4)));

#define DEV_INLINE __device__ __forceinline__

constexpr int NB = 4;        // batches
constexpr int NAG = 4096;    // agents per batch
constexpr int ROWS = NB * NAG;
constexpr int GRID = 20;     // bin grid (cell size 1.0 >= radius)
constexpr int CELLS = GRID * GRID;
constexpr int CSTRIDE = 404;
constexpr int MAXNB = 128;   // per-agent neighbor cap (lambda ~32)

DEV_INLINE u16 f2bu(float x) { __bf16 h = (__bf16)x; return __builtin_bit_cast(u16, h); }
DEV_INLINE float bu2f(u16 u) { return __builtin_bit_cast(float, ((u32)u) << 16); }
DEV_INLINE u32 pack2(float a, float b) { return (u32)f2bu(a) | ((u32)f2bu(b) << 16); }

DEV_INLINE f32x4 MF(bf16x8 a, const u16* p, f32x4 c) {
  ushort8 bu = *(const ushort8*)p;
  return __builtin_amdgcn_mfma_f32_16x16x32_bf16(a, __builtin_bit_cast(bf16x8, bu), c, 0, 0, 0);
}

template<bool BF>
DEV_INLINE bf16x8 loadA(const void* __restrict__ src, int row, int c) {
  if constexpr (BF) {
    ushort8 u = *reinterpret_cast<const ushort8*>((const u16*)src + (size_t)row * 64 + c);
    return __builtin_bit_cast(bf16x8, u);
  } else {
    const float* f = (const float*)src + (size_t)row * 64 + c;
    f32x4 a = *(const f32x4*)f;
    f32x4 b = *(const f32x4*)(f + 4);
    bf16x8 r;
    r[0] = (__bf16)a[0]; r[1] = (__bf16)a[1]; r[2] = (__bf16)a[2]; r[3] = (__bf16)a[3];
    r[4] = (__bf16)b[0]; r[5] = (__bf16)b[1]; r[6] = (__bf16)b[2]; r[7] = (__bf16)b[3];
    return r;
  }
}

// ================= K1: binning (blocks 0..3) | mlp1 (4..259) | W3-6 transpose (260..263)
// (verbatim from round 9)
__global__ __launch_bounds__(1024) void fused_setup_mlp1(
    const float* __restrict__ pos, const float* __restrict__ states,
    const float* __restrict__ W1, const float* __restrict__ b1,
    const float* __restrict__ W2, const float* __restrict__ b2,
    const float* __restrict__ W3, const float* __restrict__ W4,
    const float* __restrict__ W5, const float* __restrict__ W6,
    u16* __restrict__ wts, u16* __restrict__ msgs,
    float2* __restrict__ pos_sorted, int* __restrict__ cell_start,
    int* __restrict__ sid)
{
  extern __shared__ u16 smem[];
  const int tid = threadIdx.x;
  const int lane = tid & 63;
  const int wave = tid >> 6;
  const int bid = blockIdx.x;

  if (bid < NB) {
    int* cnt_s = (int*)smem;
    int* start_s = cnt_s + CELLS;
    u16* cell_of = (u16*)(start_s + CELLS + 1);
    u16* rank_of = cell_of + NAG;
    const float2* pb = (const float2*)(pos + (size_t)bid * NAG * 2);
    for (int c = tid; c < CELLS; c += 1024) cnt_s[c] = 0;
    __syncthreads();
    for (int i = tid; i < NAG; i += 1024) {
      float2 p = pb[i];
      int cx = min(max((int)floorf(p.x), 0), GRID - 1);
      int cy = min(max((int)floorf(p.y), 0), GRID - 1);
      int c = cy * GRID + cx;
      rank_of[i] = (u16)atomicAdd(&cnt_s[c], 1);
      cell_of[i] = (u16)c;
    }
    __syncthreads();
    if (wave == 0) {
      int carry = 0;
      for (int g = 0; g < CELLS; g += 64) {
        int c = g + lane;
        int x = (c < CELLS) ? cnt_s[c] : 0;
#pragma unroll
        for (int off = 1; off < 64; off <<= 1) {
          int y = __shfl_up(x, off, 64);
          if (lane >= off) x += y;
        }
        if (c < CELLS) start_s[c + 1] = carry + x;
        carry += __shfl(x, 63, 64);
      }
      if (lane == 0) start_s[0] = 0;
    }
    __syncthreads();
    for (int c = tid; c <= CELLS; c += 1024) cell_start[bid * CSTRIDE + c] = start_s[c];
    for (int i = tid; i < NAG; i += 1024) {
      int kk = start_s[cell_of[i]] + (int)rank_of[i];
      sid[bid * NAG + kk] = bid * NAG + i;
      pos_sorted[bid * NAG + kk] = pb[i];
    }
    return;
  }

  if (bid >= NB + 256) {
    const int base = (bid - (NB + 256)) * 12288;
#pragma unroll
    for (int t = 0; t < 12; ++t) {
      int idx = base + t * 1024 + tid;
      const float* src; int n, k, Nc;
      if (idx < 16384)      { src = W3; n = idx >> 7; k = idx & 127; Nc = 128; }
      else if (idx < 24576) { int li = idx - 16384; src = W4; n = li >> 7; k = li & 127; Nc = 64; }
      else if (idx < 40960) { int li = idx - 24576; src = W5; n = li >> 7; k = li & 127; Nc = 128; }
      else                  { int li = idx - 40960; src = W6; n = li >> 7; k = li & 127; Nc = 64; }
      wts[idx] = f2bu(src[k * Nc + n]);
    }
    return;
  }

  // ---------- mlp1 ----------
  u16* WaTs = smem;              // [128][72]
  u16* WbTs = smem + 9216;       // [64][136]
  u16* ovl  = smem + 17920;      // overlay

  const int l15 = lane & 15;
  const int khalf = (lane >> 4) * 8;
  const int rg = wave >> 2;
  const int cq = wave & 3;
  const int rb = (bid - NB) * 64 + rg * 16;
  const int row = rb + l15;

  bf16x8 aS[2];
  aS[0] = loadA<false>(states, row, khalf);
  aS[1] = loadA<false>(states, row, 32 + khalf);

  for (int t = tid; t < 4096; t += 1024) {
    const int e = t * 2;
    const int k = e >> 7, n = e & 127;
    const float2 v = *(const float2*)&W1[e];
    *(u32*)&ovl[k * 132 + n] = pack2(v.x, v.y);
  }
  __syncthreads();
  {
    const int n = tid & 127, g = tid >> 7;
    ushort8 v;
#pragma unroll
    for (int j = 0; j < 8; ++j) v[j] = ovl[(g * 8 + j) * 132 + n];
    *(ushort8*)&WaTs[n * 72 + g * 8] = v;
  }
  __syncthreads();
  for (int t = tid; t < 4096; t += 1024) {
    const int e = t * 2;
    const int k = e >> 6, n = e & 63;
    const float2 v = *(const float2*)&W2[e];
    *(u32*)&ovl[k * 68 + n] = pack2(v.x, v.y);
  }
  __syncthreads();
  {
    const int n = tid & 63, g = tid >> 6;
    ushort8 v;
#pragma unroll
    for (int j = 0; j < 8; ++j) v[j] = ovl[(g * 8 + j) * 68 + n];
    *(ushort8*)&WbTs[n * 136 + g * 8] = v;
  }
  __syncthreads();

  u16* hs = ovl + rg * 2176;

  f32x4 acc1[2] = {};
#pragma unroll
  for (int kt = 0; kt < 2; ++kt) {
#pragma unroll
    for (int j = 0; j < 2; ++j) {
      const int nt = cq * 2 + j;
      acc1[j] = MF(aS[kt], &WaTs[(nt * 16 + l15) * 72 + kt * 32 + khalf], acc1[j]);
    }
  }
#pragma unroll
  for (int j = 0; j < 2; ++j) {
    const int col = (cq * 2 + j) * 16 + l15;
    const float bv = b1[col];
#pragma unroll
    for (int r = 0; r < 4; ++r)
      hs[((lane >> 4) * 4 + r) * 136 + col] = f2bu(fmaxf(acc1[j][r] + bv, 0.0f));
  }
  __syncthreads();

  f32x4 acc2 = {};
#pragma unroll
  for (int kt = 0; kt < 4; ++kt) {
    ushort8 au = *(const ushort8*)&hs[l15 * 136 + kt * 32 + khalf];
    acc2 = MF(__builtin_bit_cast(bf16x8, au),
              &WbTs[(cq * 16 + l15) * 136 + kt * 32 + khalf], acc2);
  }
  {
    const int col = cq * 16 + l15;
    const float bv = b2[col];
#pragma unroll
    for (int r = 0; r < 4; ++r)
      msgs[(size_t)(rb + (lane >> 4) * 4 + r) * 64 + col] = f2bu(acc2[r] + bv);
  }
}

// ================= K2: aggregation — mask phase as before; wide-quad gather.
// lane = (s=row-slot)<<4 | (q=channel-quad). One round: 4 neighbor rows via
// dwordx2 loads (8B/lane). Cross-slot reduce: shfl_xor 16/32. 16-lane store.
__global__ __launch_bounds__(256) void agg_kernel(
    const float2* __restrict__ pos_sorted, const u16* __restrict__ msgs,
    const int* __restrict__ cell_start, const int* __restrict__ sid,
    const int* __restrict__ radius_ptr, u16* __restrict__ aggr)
{
  __shared__ u16 idxb[4][MAXNB];
  const int b = blockIdx.y;
  const int lane = threadIdx.x & 63;
  const int wave = threadIdx.x >> 6;
  const int k = blockIdx.x * 4 + wave;
  const float2* pb = pos_sorted + (size_t)b * NAG;
  const float2 pk = pb[k];
  const float r = (float)(*radius_ptr);
  const float r2 = __fmul_rn(r, r);
  const int cx = min(max((int)floorf(pk.x), 0), GRID - 1);
  const int cy = min(max((int)floorf(pk.y), 0), GRID - 1);
  const int* cs = cell_start + b * CSTRIDE;
  const int* sb = sid + b * NAG;
  const unsigned long long lt = (1ull << lane) - 1ull;

  // ---- mask phase (unchanged) ----
  int cnt = 0;
#pragma unroll
  for (int dy = -1; dy <= 1; ++dy) {
    const int yy = cy + dy;
    if (yy < 0 || yy >= GRID) continue;
    const int x0 = max(cx - 1, 0), x1 = min(cx + 1, GRID - 1);
    const int c0 = cs[yy * GRID + x0];
    const int c1 = cs[yy * GRID + x1 + 1];
    for (int base = c0; base < c1; base += 64) {
      const int j = base + lane;
      bool ok = false;
      if (j < c1) {
        const float2 pj = pb[j];
        const float dx_ = pk.x - pj.x;
        const float dy_ = pk.y - pj.y;
        const float d2 = __fadd_rn(__fmul_rn(dx_, dx_), __fmul_rn(dy_, dy_));
        ok = (d2 < r2) && (j != k);
      }
      const unsigned long long m = __ballot(ok);
      if (ok) {
        const int p = cnt + __popcll(m & lt);
        if (p < MAXNB) idxb[wave][p] = (u16)sb[j];   // ORIGINAL global row
      }
      cnt += (int)__popcll(m);
    }
  }

  // ---- wide-quad gather ----
  const int q = lane & 15;     // channel quad: channels 4q..4q+3
  const int s = lane >> 4;     // row slot 0..3
  const int n = min(cnt, MAXNB);
  float a0 = 0.0f, a1 = 0.0f, a2 = 0.0f, a3 = 0.0f;
  const int nfull = n & ~3;
  for (int g = 0; g < nfull; g += 4) {
    const int jj = (int)idxb[wave][g + s];
    const uint2 v = *(const uint2*)(msgs + (size_t)jj * 64 + q * 4);
    a0 += __builtin_bit_cast(float, v.x << 16);
    a1 += __builtin_bit_cast(float, v.x & 0xffff0000u);
    a2 += __builtin_bit_cast(float, v.y << 16);
    a3 += __builtin_bit_cast(float, v.y & 0xffff0000u);
  }
  const int t = n - nfull;
  if (s < t) {
    const int jj = (int)idxb[wave][nfull + s];
    const uint2 v = *(const uint2*)(msgs + (size_t)jj * 64 + q * 4);
    a0 += __builtin_bit_cast(float, v.x << 16);
    a1 += __builtin_bit_cast(float, v.x & 0xffff0000u);
    a2 += __builtin_bit_cast(float, v.y << 16);
    a3 += __builtin_bit_cast(float, v.y & 0xffff0000u);
  }
  // reduce across the 4 row-slots (butterfly leaves total in all lanes)
  a0 += __shfl_xor(a0, 16); a1 += __shfl_xor(a1, 16);
  a2 += __shfl_xor(a2, 16); a3 += __shfl_xor(a3, 16);
  a0 += __shfl_xor(a0, 32); a1 += __shfl_xor(a1, 32);
  a2 += __shfl_xor(a2, 32); a3 += __shfl_xor(a3, 32);

  if (s == 0) {
    const float inv = 1.0f / (float)(cnt > 0 ? cnt : 1);
    const int orow = sb[k];
    uint2 w;
    w.x = pack2(a0 * inv, a1 * inv);
    w.y = pack2(a2 * inv, a3 * inv);
    *(uint2*)(aggr + (size_t)orow * 64 + q * 4) = w;
  }
}

// ================= K3: fused MLP2+MLP3 (verbatim from round 9)
__global__ __launch_bounds__(1024, 4) void mlp23_kernel(
    const float* __restrict__ states, const u16* __restrict__ msgs,
    const u16* __restrict__ aggr, const u16* __restrict__ wts,
    const float* __restrict__ b3, const float* __restrict__ b4,
    const float* __restrict__ b5, const float* __restrict__ b6,
    float* __restrict__ out)
{
  extern __shared__ u16 smem[];
  u16* W3s = smem;                  // [128][136]
  u16* W4s = W3s + 128 * 136;       // [64][136]
  u16* W5s = W4s + 64 * 136;        // [128][136]
  u16* W6s = W5s + 128 * 136;       // [64][136]
  u16* hsb = W6s + 64 * 136;        // [4][16*136]
  u16* fsb = hsb + 4 * 16 * 136;    // [4][16*136]

  const int tid = threadIdx.x;
  const int lane = tid & 63;
  const int wave = tid >> 6;        // 0..15
  const int rg = wave >> 2;         // row-group 0..3
  const int cq = wave & 3;          // col-quarter 0..3
  const int l15 = lane & 15;
  const int khalf = (lane >> 4) * 8;
  const int rb = blockIdx.x * 64 + rg * 16;
  const int row = rb + l15;
  u16* hs = hsb + rg * (16 * 136);
  u16* fs = fsb + rg * (16 * 136);

  bf16x8 aM[2], aG[2], aS[2];
  aM[0] = loadA<true>(msgs, row, khalf);
  aM[1] = loadA<true>(msgs, row, 32 + khalf);
  aG[0] = loadA<true>(aggr, row, khalf);
  aG[1] = loadA<true>(aggr, row, 32 + khalf);
  aS[0] = loadA<false>(states, row, khalf);
  aS[1] = loadA<false>(states, row, 32 + khalf);

  for (int t = tid; t < 6144; t += 1024) {
    const int e = t * 8;
    ushort8 v = *(const ushort8*)&wts[e];
    u16* dst;
    if (e < 16384)      dst = &W3s[(e >> 7) * 136 + (e & 127)];
    else if (e < 24576) { int li = e - 16384; dst = &W4s[(li >> 7) * 136 + (li & 127)]; }
    else if (e < 40960) { int li = e - 24576; dst = &W5s[(li >> 7) * 136 + (li & 127)]; }
    else                { int li = e - 40960; dst = &W6s[(li >> 7) * 136 + (li & 127)]; }
    *(ushort8*)dst = v;
  }
  __syncthreads();

  f32x4 acc1[2] = {};
#pragma unroll
  for (int kt = 0; kt < 4; ++kt) {
    bf16x8 a = (kt < 2) ? aM[kt] : aG[kt - 2];
#pragma unroll
    for (int j = 0; j < 2; ++j) {
      const int nt = cq * 2 + j;
      acc1[j] = MF(a, &W3s[(nt * 16 + l15) * 136 + kt * 32 + khalf], acc1[j]);
    }
  }
#pragma unroll
  for (int j = 0; j < 2; ++j) {
    const int col = (cq * 2 + j) * 16 + l15;
    const float bv = b3[col];
#pragma unroll
    for (int r = 0; r < 4; ++r)
      hs[((lane >> 4) * 4 + r) * 136 + col] = f2bu(fmaxf(acc1[j][r] + bv, 0.0f));
  }
  __syncthreads();

  f32x4 acc2 = {};
#pragma unroll
  for (int kt = 0; kt < 4; ++kt) {
    ushort8 au = *(const ushort8*)&hs[l15 * 136 + kt * 32 + khalf];
    acc2 = MF(__builtin_bit_cast(bf16x8, au),
              &W4s[(cq * 16 + l15) * 136 + kt * 32 + khalf], acc2);
  }
  {
    const int col = cq * 16 + l15;
    const float bv = b4[col];
#pragma unroll
    for (int r = 0; r < 4; ++r)
      fs[((lane >> 4) * 4 + r) * 136 + col] = f2bu(acc2[r] + bv);
  }
  __syncthreads();

  f32x4 acc3[2] = {};
#pragma unroll
  for (int kt = 0; kt < 4; ++kt) {
    bf16x8 a;
    if (kt < 2) a = aS[kt];
    else {
      ushort8 au = *(const ushort8*)&fs[l15 * 136 + (kt - 2) * 32 + khalf];
      a = __builtin_bit_cast(bf16x8, au);
    }
#pragma unroll
    for (int j = 0; j < 2; ++j) {
      const int nt = cq * 2 + j;
      acc3[j] = MF(a, &W5s[(nt * 16 + l15) * 136 + kt * 32 + khalf], acc3[j]);
    }
  }
#pragma unroll
  for (int j = 0; j < 2; ++j) {
    const int col = (cq * 2 + j) * 16 + l15;
    const float bv = b5[col];
#pragma unroll
    for (int r = 0; r < 4; ++r)
      hs[((lane >> 4) * 4 + r) * 136 + col] = f2bu(fmaxf(acc3[j][r] + bv, 0.0f));
  }
  __syncthreads();

  f32x4 acc4 = {};
#pragma unroll
  for (int kt = 0; kt < 4; ++kt) {
    ushort8 au = *(const ushort8*)&hs[l15 * 136 + kt * 32 + khalf];
    acc4 = MF(__builtin_bit_cast(bf16x8, au),
              &W6s[(cq * 16 + l15) * 136 + kt * 32 + khalf], acc4);
  }
  {
    const int col = cq * 16 + l15;
    const float bv = b6[col];
#pragma unroll
    for (int r = 0; r < 4; ++r) {
      const int m = (lane >> 4) * 4 + r;
      const size_t o = (size_t)(rb + m) * 64 + col;
      out[o] = acc4[r] + bv + states[o];
    }
  }
}

// ================= launch
extern "C" void kernel_launch(void* const* d_in, const int* in_sizes, int n_in,
                              void* d_out, int out_size, void* d_ws, size_t ws_size,
                              hipStream_t stream) {
  const float* states = (const float*)d_in[0];
  const float* pos    = (const float*)d_in[1];
  const int*   radius = (const int*)d_in[2];
  const float* W1 = (const float*)d_in[3];
  const float* b1 = (const float*)d_in[4];
  const float* W2 = (const float*)d_in[5];
  const float* b2 = (const float*)d_in[6];
  const float* W3 = (const float*)d_in[7];
  const float* b3 = (const float*)d_in[8];
  const float* W4 = (const float*)d_in[9];
  const float* b4 = (const float*)d_in[10];
  const float* W5 = (const float*)d_in[11];
  const float* b5 = (const float*)d_in[12];
  const float* W6 = (const float*)d_in[13];
  const float* b6 = (const float*)d_in[14];
  float* out = (float*)d_out;

  u16* ws16 = (u16*)d_ws;
  u16* msgs = ws16;                         // [ROWS][64] bf16 (orig order)
  u16* aggr = msgs + (size_t)ROWS * 64;     // [ROWS][64] bf16 (orig order)
  u16* wts  = aggr + (size_t)ROWS * 64;     // 49152 bf16 W3T..W6T
  char* pbyte = (char*)(wts + 49152);
  float2* pos_sorted = (float2*)pbyte;                 // ROWS float2
  int* cell_start = (int*)(pbyte + (size_t)ROWS * 8);  // NB*CSTRIDE
  int* sid = cell_start + NB * CSTRIDE;                // ROWS

  constexpr int LDS_K1 = 26624 * 2;                    // 53248
  constexpr int LDS_K3 = (384 * 136 + 8 * 16 * 136) * 2;  // 139264

  fused_setup_mlp1<<<NB + 256 + 4, 1024, LDS_K1, stream>>>(
      pos, states, W1, b1, W2, b2, W3, W4, W5, W6,
      wts, msgs, pos_sorted, cell_start, sid);

  agg_kernel<<<dim3(NAG / 4, NB), 256, 0, stream>>>(
      pos_sorted, msgs, cell_start, sid, radius, aggr);

  mlp23_kernel<<<ROWS / 64, 1024, LDS_K3, stream>>>(
      states, msgs, aggr, wts, b3, b4, b5, b6, out);
}